// Round 3
// baseline (747.344 us; speedup 1.0000x reference)
//
#include <hip/hip_runtime.h>

typedef short s8v __attribute__((ext_vector_type(8)));
typedef float f32x4 __attribute__((ext_vector_type(4)));

#define PAD 72   // padded LDS k-stride (bf16 elems) for tkern transpose

__device__ __forceinline__ unsigned short f2bf(float x) {
    unsigned int u = __float_as_uint(x);
    u += 0x7fffu + ((u >> 16) & 1u);   // RNE
    return (unsigned short)(u >> 16);
}

// ---------------- barrier-free streaming GEMM ----------------
// C[m][f] = sum_k A[m][k] * B[k][f]
//   A: fp32 [M][lda] row-major, streamed from HBM (read-once)
//   Bt: bf16 stored transposed [128 f][ldb k], L2/L3-resident
// Block = 256 threads = 4 waves; wave w computes rows [blk*128 + w*32, +32) x all 128 cols.
// Split-K via blockIdx.y: k range [y*klen, +klen), fp32 partial slab at C + y*M*128.
// No LDS, no __syncthreads. Latency hiding = 2-deep even/odd register prefetch
// (compiler-counted vmcnt) x 8 waves/CU (launch_bounds(256,2), grid 2 blocks/CU).

struct ASet { float4 a[4]; };   // a[m*2+h]: m-frag m (rows +0/+16), k half h
struct BSet { s8v  b[8];  };    // b[nt]: n-tile nt (cols nt*16..+16)

__device__ __forceinline__ void loadA(ASet& S, const float* Ap0, const float* Ap1, int ko) {
    S.a[0] = *(const float4*)(Ap0 + ko);
    S.a[1] = *(const float4*)(Ap0 + ko + 4);
    S.a[2] = *(const float4*)(Ap1 + ko);
    S.a[3] = *(const float4*)(Ap1 + ko + 4);
}

__device__ __forceinline__ void loadB(BSet& S, const unsigned short* Bp, int ko, int ldb) {
    #pragma unroll
    for (int nt = 0; nt < 8; ++nt)
        S.b[nt] = *(const s8v*)(Bp + (size_t)nt * 16 * ldb + ko);
}

__device__ __forceinline__ s8v cvt8(float4 lo, float4 hi) {
    s8v r;
    r[0] = (short)f2bf(lo.x); r[1] = (short)f2bf(lo.y);
    r[2] = (short)f2bf(lo.z); r[3] = (short)f2bf(lo.w);
    r[4] = (short)f2bf(hi.x); r[5] = (short)f2bf(hi.y);
    r[6] = (short)f2bf(hi.z); r[7] = (short)f2bf(hi.w);
    return r;
}

__device__ __forceinline__ void compute(f32x4 (&acc)[2][8], const ASet& AS, const BSet& BS) {
    s8v af0 = cvt8(AS.a[0], AS.a[1]);
    s8v af1 = cvt8(AS.a[2], AS.a[3]);
    #pragma unroll
    for (int nt = 0; nt < 8; ++nt) {
        acc[0][nt] = __builtin_amdgcn_mfma_f32_16x16x32_bf16(af0, BS.b[nt], acc[0][nt], 0, 0, 0);
        acc[1][nt] = __builtin_amdgcn_mfma_f32_16x16x32_bf16(af1, BS.b[nt], acc[1][nt], 0, 0, 0);
    }
}

__global__ __launch_bounds__(256, 2) void gemm_stream(
    const float* __restrict__ A, int lda,
    const unsigned short* __restrict__ Bt, int ldb,
    float* __restrict__ C, int klen)
{
    const int t    = threadIdx.x;
    const int wave = t >> 6;
    const int lane = t & 63;
    const int quad = lane >> 4;
    const int l16  = lane & 15;

    const int mbase = blockIdx.x * 128 + wave * 32;
    const int k0    = blockIdx.y * klen;
    C += (size_t)blockIdx.y * ((size_t)gridDim.x * 128 * 128);

    // A-frag: lane holds A[row = l16 (+16)][k = quad*8 + j]
    const float* Ap0 = A + (size_t)(mbase + l16) * lda + k0 + quad * 8;
    const float* Ap1 = Ap0 + (size_t)16 * lda;
    // B-frag: lane holds Bt[col = nt*16 + l16][k = quad*8 + j]
    const unsigned short* Bp = Bt + (size_t)l16 * ldb + k0 + quad * 8;

    const int nsteps = klen / 32;   // even, >= 4 for all call sites

    f32x4 acc[2][8];
    #pragma unroll
    for (int m = 0; m < 2; ++m)
        #pragma unroll
        for (int n = 0; n < 8; ++n)
            acc[m][n] = (f32x4){0.f, 0.f, 0.f, 0.f};

    ASet Ae, Ao; BSet Be, Bo;
    loadA(Ae, Ap0, Ap1, 0);   loadA(Ao, Ap0, Ap1, 32);   // A first: longest latency
    loadB(Be, Bp, 0, ldb);    loadB(Bo, Bp, 32, ldb);

    for (int s = 0; s < nsteps - 2; s += 2) {
        compute(acc, Ae, Be);
        loadA(Ae, Ap0, Ap1, (s + 2) * 32);
        loadB(Be, Bp, (s + 2) * 32, ldb);
        compute(acc, Ao, Bo);
        loadA(Ao, Ap0, Ap1, (s + 3) * 32);
        loadB(Bo, Bp, (s + 3) * 32, ldb);
    }
    compute(acc, Ae, Be);
    compute(acc, Ao, Bo);

    // C/D layout: col = l16 (within 16-col tile), row = quad*4 + i
    const int row0 = mbase + quad * 4;
    #pragma unroll
    for (int m = 0; m < 2; ++m)
        #pragma unroll
        for (int nt = 0; nt < 8; ++nt)
            #pragma unroll
            for (int i = 0; i < 4; ++i)
                C[(size_t)(row0 + m * 16 + i) * 128 + nt * 16 + l16] = acc[m][nt][i];
}

// ---------------- transpose / reduce / scale / convert ----------------
// a: nslab slabs of [nrows][128] fp32 (slab stride nrows*128).
// out[f][k] = bf16( scale(k) * sum_slabs a[s][k][f] ), out row stride = nrows.
// mode==1: scale(k) = sum_j dl[j][k]^2 * ft[j][k], else scale = 1.
__global__ __launch_bounds__(256) void tkern(
    const float* __restrict__ a,
    const float* __restrict__ dl, const float* __restrict__ ft,
    unsigned short* __restrict__ out, int nrows, int nslab, int mode)
{
    __shared__ __align__(16) unsigned short L[128 * PAD];
    const int t    = threadIdx.x;
    const int kb   = blockIdx.x * 64;
    const int kloc = t >> 2;
    const int fseg = (t & 3) * 32;
    const int k    = kb + kloc;

    float s = 1.0f;
    if (mode) {
        float s0 = 0.f;
        #pragma unroll
        for (int j = 0; j < 3; ++j) {
            float d = dl[(size_t)j * nrows + k];
            s0 += d * d * ft[(size_t)j * nrows + k];
        }
        s = s0;
    }
    const size_t sstride = (size_t)nrows * 128;
    const float* ap = a + (size_t)k * 128 + fseg;
    #pragma unroll
    for (int i = 0; i < 8; ++i) {
        float4 v = *(const float4*)(ap + i * 4);
        for (int sl = 1; sl < nslab; ++sl) {
            float4 w = *(const float4*)(ap + (size_t)sl * sstride + i * 4);
            v.x += w.x; v.y += w.y; v.z += w.z; v.w += w.w;
        }
        const int fb = fseg + i * 4;
        L[(fb + 0) * PAD + kloc] = f2bf(v.x * s);
        L[(fb + 1) * PAD + kloc] = f2bf(v.y * s);
        L[(fb + 2) * PAD + kloc] = f2bf(v.z * s);
        L[(fb + 3) * PAD + kloc] = f2bf(v.w * s);
    }
    __syncthreads();
    const int f    = t >> 1;
    const int half = (t & 1) * 32;
    unsigned short* op = out + (size_t)f * nrows + kb + half;
    #pragma unroll
    for (int i = 0; i < 4; ++i)
        *(s8v*)(op + i * 8) = *(const s8v*)&L[f * PAD + half + i * 8];
}

// out = bias + sum over nslab partial slabs [8192][128]
__global__ __launch_bounds__(256) void reduce_bias(
    const float* __restrict__ p, const float* __restrict__ bias,
    float* __restrict__ out, int nslab)
{
    const size_t NF = (size_t)8192 * 128;
    const size_t e  = ((size_t)blockIdx.x * 256 + threadIdx.x) * 4;
    float4 r = *(const float4*)(bias + (e & 127));
    for (int s = 0; s < nslab; ++s) {
        float4 x = *(const float4*)(p + (size_t)s * NF + e);
        r.x += x.x; r.y += x.y; r.z += x.z; r.w += x.w;
    }
    *(float4*)(out + e) = r;
}

extern "C" void kernel_launch(void* const* d_in, const int* in_sizes, int n_in,
                              void* d_out, int out_size, void* d_ws, size_t ws_size,
                              hipStream_t stream)
{
    const float* x  = (const float*)d_in[0];   // [8192][128]
    const float* dl = (const float*)d_in[1];   // [3][8192]
    const float* U  = (const float*)d_in[2];   // [8192][8192]
    const float* Vt = (const float*)d_in[3];   // [8192][8192]
    const float* W  = (const float*)d_in[4];   // [128][128]
    const float* ft = (const float*)d_in[5];   // [3][8192]
    const float* bs = (const float*)d_in[6];   // [128]
    float* out = (float*)d_out;

    const int N = 8192, F = 128;
    char* ws = (char*)d_ws;
    unsigned short* Wt  = (unsigned short*)(ws);                    // 32KB (64KB reserved)
    unsigned short* xwt = (unsigned short*)(ws + (64 << 10));       // 2MB  bf16 [128][8192]
    unsigned short* yt  = (unsigned short*)(ws + (64 << 10) + (2 << 20)); // 2MB bf16 [128][8192]
    // 32MB region: first holds xw fp32 [8192][128] (slab 0 slot), later 8 partial slabs
    float* P = (float*)(ws + (64 << 10) + (4 << 20));

    // T0: Wt[f][c] = bf16(W[c][f])
    tkern<<<dim3(F / 64), 256, 0, stream>>>(W, nullptr, nullptr, Wt, F, 1, 0);
    // G1: xw = x @ W   (single K pass, writes P slab 0)
    gemm_stream<<<dim3(N / 128, 1), 256, 0, stream>>>(x, F, Wt, F, P, F);
    // T1: xwt[f][n] = bf16(xw[n][f])
    tkern<<<dim3(N / 64), 256, 0, stream>>>(P, nullptr, nullptr, xwt, N, 1, 0);
    // G2: P[s] = partial Vt @ xw  (split-K 8, 512 blocks = 2/CU)
    gemm_stream<<<dim3(N / 128, 8), 256, 0, stream>>>(Vt, N, xwt, N, P, N / 8);
    // T2: yt[f][k] = bf16( scale(k) * sum_s P[s][k][f] )
    tkern<<<dim3(N / 64), 256, 0, stream>>>(P, dl, ft, yt, N, 8, 1);
    // G3: P[s] = partial U @ y  (split-K 8)
    gemm_stream<<<dim3(N / 128, 8), 256, 0, stream>>>(U, N, yt, N, P, N / 8);
    // T3: out = sum_s P[s] + bias
    reduce_bias<<<dim3((N * F) / (256 * 4)), 256, 0, stream>>>(P, bs, out, 8);
}

// Round 4
// 619.721 us; speedup vs baseline: 1.2059x; 1.2059x over previous
//
#include <hip/hip_runtime.h>

typedef short s8v __attribute__((ext_vector_type(8)));
typedef float f32x4 __attribute__((ext_vector_type(4)));

#define PAD 72   // padded LDS k-stride (bf16 elems) for tkern transpose

__device__ __forceinline__ unsigned short f2bf(float x) {
    unsigned int u = __float_as_uint(x);
    u += 0x7fffu + ((u >> 16) & 1u);   // RNE
    return (unsigned short)(u >> 16);
}

// ---------------- barrier-free streaming GEMM ----------------
// C[m][f] = sum_k A[m][k] * B[k][f]
//   A: fp32 [M][lda] row-major, streamed from HBM (read-once)
//   Bt: bf16 stored transposed [128 f][ldb k], L2/L3-resident
// Block = 256 threads = 4 waves; wave w computes rows [blk*128 + w*32, +32) x all 128 cols.
// Split-K via blockIdx.y: fp32 partial slab at C + y*M*128.
//
// Latency model (Little's law): sustained A-BW = in-flight bytes / loaded latency.
// 4-deep NAMED rings for BOTH A and B (static indexing only), B issued before A
// within each step, so no wait point ever drains the deep A-prefetch
// (vmcnt is in-order: the shortest issue-to-use distance gates everything).
// launch_bounds(256,1): full VGPR budget, compiler has no occupancy excuse to
// collapse the ring. 4 waves/CU x 3 steps x 4KB = 48KB A in flight per CU.

struct ASet { float4 a[4]; };   // a[m*2+h]: m-frag m (rows +0/+16), k half h
struct BSet { s8v  b[8];  };    // b[nt]: n-tile nt (cols nt*16..+16)

__device__ __forceinline__ void loadA(ASet& S, const float* Ap0, const float* Ap1, int ko) {
    S.a[0] = *(const float4*)(Ap0 + ko);
    S.a[1] = *(const float4*)(Ap0 + ko + 4);
    S.a[2] = *(const float4*)(Ap1 + ko);
    S.a[3] = *(const float4*)(Ap1 + ko + 4);
}

__device__ __forceinline__ void loadB(BSet& S, const unsigned short* Bp, int ko, int ldb) {
    #pragma unroll
    for (int nt = 0; nt < 8; ++nt)
        S.b[nt] = *(const s8v*)(Bp + (size_t)nt * 16 * ldb + ko);
}

__device__ __forceinline__ s8v cvt8(float4 lo, float4 hi) {
    s8v r;
    r[0] = (short)f2bf(lo.x); r[1] = (short)f2bf(lo.y);
    r[2] = (short)f2bf(lo.z); r[3] = (short)f2bf(lo.w);
    r[4] = (short)f2bf(hi.x); r[5] = (short)f2bf(hi.y);
    r[6] = (short)f2bf(hi.z); r[7] = (short)f2bf(hi.w);
    return r;
}

__device__ __forceinline__ void compute(f32x4 (&acc)[2][8], const ASet& AS, const BSet& BS) {
    s8v af0 = cvt8(AS.a[0], AS.a[1]);
    s8v af1 = cvt8(AS.a[2], AS.a[3]);
    #pragma unroll
    for (int nt = 0; nt < 8; ++nt) {
        acc[0][nt] = __builtin_amdgcn_mfma_f32_16x16x32_bf16(af0, BS.b[nt], acc[0][nt], 0, 0, 0);
        acc[1][nt] = __builtin_amdgcn_mfma_f32_16x16x32_bf16(af1, BS.b[nt], acc[1][nt], 0, 0, 0);
    }
}

__global__ __launch_bounds__(256, 1) void gemm_stream(
    const float* __restrict__ A, int lda,
    const unsigned short* __restrict__ Bt, int ldb,
    float* __restrict__ C, int klen)
{
    const int t    = threadIdx.x;
    const int wave = t >> 6;
    const int lane = t & 63;
    const int quad = lane >> 4;
    const int l16  = lane & 15;

    const int mbase = blockIdx.x * 128 + wave * 32;
    const int k0    = blockIdx.y * klen;
    C += (size_t)blockIdx.y * ((size_t)gridDim.x * 128 * 128);

    // A-frag: lane holds A[row = l16 (+16)][k = quad*8 + j]
    const float* Ap0 = A + (size_t)(mbase + l16) * lda + k0 + quad * 8;
    const float* Ap1 = Ap0 + (size_t)16 * lda;
    // B-frag: lane holds Bt[col = nt*16 + l16][k = quad*8 + j]
    const unsigned short* Bp = Bt + (size_t)l16 * ldb + k0 + quad * 8;

    const int nsteps = klen / 32;   // multiple of 4 at all call sites (4 or 512)

    f32x4 acc[2][8];
    #pragma unroll
    for (int m = 0; m < 2; ++m)
        #pragma unroll
        for (int n = 0; n < 8; ++n)
            acc[m][n] = (f32x4){0.f, 0.f, 0.f, 0.f};

    ASet A0, A1, A2, A3; BSet B0, B1, B2, B3;
    loadB(B0, Bp, 0 * 32, ldb);  loadA(A0, Ap0, Ap1, 0 * 32);
    loadB(B1, Bp, 1 * 32, ldb);  loadA(A1, Ap0, Ap1, 1 * 32);
    loadB(B2, Bp, 2 * 32, ldb);  loadA(A2, Ap0, Ap1, 2 * 32);
    loadB(B3, Bp, 3 * 32, ldb);  loadA(A3, Ap0, Ap1, 3 * 32);

    for (int s = 0; s < nsteps - 4; s += 4) {
        // each step: compute(step s+i), then issue loads for step s+4+i.
        // B issued before A so a wait on B never drains a deeper A prefetch.
        compute(acc, A0, B0); loadB(B0, Bp, (s + 4) * 32, ldb); loadA(A0, Ap0, Ap1, (s + 4) * 32);
        compute(acc, A1, B1); loadB(B1, Bp, (s + 5) * 32, ldb); loadA(A1, Ap0, Ap1, (s + 5) * 32);
        compute(acc, A2, B2); loadB(B2, Bp, (s + 6) * 32, ldb); loadA(A2, Ap0, Ap1, (s + 6) * 32);
        compute(acc, A3, B3); loadB(B3, Bp, (s + 7) * 32, ldb); loadA(A3, Ap0, Ap1, (s + 7) * 32);
    }
    compute(acc, A0, B0);
    compute(acc, A1, B1);
    compute(acc, A2, B2);
    compute(acc, A3, B3);

    // C/D layout: col = l16 (within 16-col tile), row = quad*4 + i
    const int row0 = mbase + quad * 4;
    #pragma unroll
    for (int m = 0; m < 2; ++m)
        #pragma unroll
        for (int nt = 0; nt < 8; ++nt)
            #pragma unroll
            for (int i = 0; i < 4; ++i)
                C[(size_t)(row0 + m * 16 + i) * 128 + nt * 16 + l16] = acc[m][nt][i];
}

// ---------------- transpose / reduce / scale / convert ----------------
// a: nslab slabs of [nrows][128] fp32 (slab stride nrows*128).
// out[f][k] = bf16( scale(k) * sum_slabs a[s][k][f] ), out row stride = nrows.
// mode==1: scale(k) = sum_j dl[j][k]^2 * ft[j][k], else scale = 1.
__global__ __launch_bounds__(256) void tkern(
    const float* __restrict__ a,
    const float* __restrict__ dl, const float* __restrict__ ft,
    unsigned short* __restrict__ out, int nrows, int nslab, int mode)
{
    __shared__ __align__(16) unsigned short L[128 * PAD];
    const int t    = threadIdx.x;
    const int kb   = blockIdx.x * 64;
    const int kloc = t >> 2;
    const int fseg = (t & 3) * 32;
    const int k    = kb + kloc;

    float s = 1.0f;
    if (mode) {
        float s0 = 0.f;
        #pragma unroll
        for (int j = 0; j < 3; ++j) {
            float d = dl[(size_t)j * nrows + k];
            s0 += d * d * ft[(size_t)j * nrows + k];
        }
        s = s0;
    }
    const size_t sstride = (size_t)nrows * 128;
    const float* ap = a + (size_t)k * 128 + fseg;
    #pragma unroll
    for (int i = 0; i < 8; ++i) {
        float4 v = *(const float4*)(ap + i * 4);
        for (int sl = 1; sl < nslab; ++sl) {
            float4 w = *(const float4*)(ap + (size_t)sl * sstride + i * 4);
            v.x += w.x; v.y += w.y; v.z += w.z; v.w += w.w;
        }
        const int fb = fseg + i * 4;
        L[(fb + 0) * PAD + kloc] = f2bf(v.x * s);
        L[(fb + 1) * PAD + kloc] = f2bf(v.y * s);
        L[(fb + 2) * PAD + kloc] = f2bf(v.z * s);
        L[(fb + 3) * PAD + kloc] = f2bf(v.w * s);
    }
    __syncthreads();
    const int f    = t >> 1;
    const int half = (t & 1) * 32;
    unsigned short* op = out + (size_t)f * nrows + kb + half;
    #pragma unroll
    for (int i = 0; i < 4; ++i)
        *(s8v*)(op + i * 8) = *(const s8v*)&L[f * PAD + half + i * 8];
}

// out = bias + sum over nslab partial slabs [8192][128]
__global__ __launch_bounds__(256) void reduce_bias(
    const float* __restrict__ p, const float* __restrict__ bias,
    float* __restrict__ out, int nslab)
{
    const size_t NF = (size_t)8192 * 128;
    const size_t e  = ((size_t)blockIdx.x * 256 + threadIdx.x) * 4;
    float4 r = *(const float4*)(bias + (e & 127));
    for (int s = 0; s < nslab; ++s) {
        float4 x = *(const float4*)(p + (size_t)s * NF + e);
        r.x += x.x; r.y += x.y; r.z += x.z; r.w += x.w;
    }
    *(float4*)(out + e) = r;
}

extern "C" void kernel_launch(void* const* d_in, const int* in_sizes, int n_in,
                              void* d_out, int out_size, void* d_ws, size_t ws_size,
                              hipStream_t stream)
{
    const float* x  = (const float*)d_in[0];   // [8192][128]
    const float* dl = (const float*)d_in[1];   // [3][8192]
    const float* U  = (const float*)d_in[2];   // [8192][8192]
    const float* Vt = (const float*)d_in[3];   // [8192][8192]
    const float* W  = (const float*)d_in[4];   // [128][128]
    const float* ft = (const float*)d_in[5];   // [3][8192]
    const float* bs = (const float*)d_in[6];   // [128]
    float* out = (float*)d_out;

    const int N = 8192, F = 128;
    char* ws = (char*)d_ws;
    unsigned short* Wt  = (unsigned short*)(ws);                    // 32KB (64KB reserved)
    unsigned short* xwt = (unsigned short*)(ws + (64 << 10));       // 2MB  bf16 [128][8192]
    unsigned short* yt  = (unsigned short*)(ws + (64 << 10) + (2 << 20)); // 2MB bf16 [128][8192]
    // 16MB region: first holds xw fp32 [8192][128] (slab 0 slot), later 4 partial slabs
    float* P = (float*)(ws + (64 << 10) + (4 << 20));

    // T0: Wt[f][c] = bf16(W[c][f])
    tkern<<<dim3(F / 64), 256, 0, stream>>>(W, nullptr, nullptr, Wt, F, 1, 0);
    // G1: xw = x @ W   (single K pass, writes P slab 0; nsteps = 4)
    gemm_stream<<<dim3(N / 128, 1), 256, 0, stream>>>(x, F, Wt, F, P, F);
    // T1: xwt[f][n] = bf16(xw[n][f])
    tkern<<<dim3(N / 64), 256, 0, stream>>>(P, nullptr, nullptr, xwt, N, 1, 0);
    // G2: P[s] = partial Vt @ xw  (split-K 4, 256 blocks = 1/CU)
    gemm_stream<<<dim3(N / 128, 4), 256, 0, stream>>>(Vt, N, xwt, N, P, N / 4);
    // T2: yt[f][k] = bf16( scale(k) * sum_s P[s][k][f] )
    tkern<<<dim3(N / 64), 256, 0, stream>>>(P, dl, ft, yt, N, 4, 1);
    // G3: P[s] = partial U @ y  (split-K 4)
    gemm_stream<<<dim3(N / 128, 4), 256, 0, stream>>>(U, N, yt, N, P, N / 4);
    // T3: out = sum_s P[s] + bias
    reduce_bias<<<dim3((N * F) / (256 * 4)), 256, 0, stream>>>(P, bs, out, 4);
}